// Round 7
// baseline (223.999 us; speedup 1.0000x reference)
//
#include <hip/hip_runtime.h>
#include <cstddef>

#define B_SZ 16
#define HW 1024
#define CCH 512
#define K_LEN 256
#define N_HEADS 8
#define EPS 1e-5f

typedef __bf16 bf16;
typedef bf16 bf16x8 __attribute__((ext_vector_type(8)));
typedef bf16 bf16x4 __attribute__((ext_vector_type(4)));
typedef float f32x4 __attribute__((ext_vector_type(4)));

// async global->LDS, 16B per lane; LDS dest is wave-uniform base + lane*16
__device__ __forceinline__ void gl_lds16(const bf16* g, bf16* l) {
    __builtin_amdgcn_global_load_lds(
        (const __attribute__((address_space(1))) void*)g,
        (__attribute__((address_space(3))) void*)l, 16, 0, 0);
}

// ---------------------------------------------------------------------------
// Merged transpose+cast: z<16 -> img [B][512][1024] f32 -> [B][1024][512] bf16
//                        z>=16 -> weights W[k][n] f32 -> Wt[n][k] bf16 packed
// ---------------------------------------------------------------------------
__global__ __launch_bounds__(256) void tc_all(
    const float* __restrict__ img,
    const float* __restrict__ Wq, const float* __restrict__ Wk,
    const float* __restrict__ Wv, const float* __restrict__ Wo,
    bf16* __restrict__ img_bf, bf16* __restrict__ wT)
{
    __shared__ bf16 T[64][72];
    const int tid = threadIdx.x;
    const int z = blockIdx.z;
    if (z < 16) {
        const int b = z, s0 = blockIdx.x * 64, c0 = blockIdx.y * 64;
        {
            const int r = tid >> 2, cs = (tid & 3) << 4;
            const float* sp = img + ((size_t)b * CCH + c0 + r) * HW + s0 + cs;
            #pragma unroll
            for (int i = 0; i < 4; ++i) {
                float4 f = *(const float4*)(sp + i * 4);
                T[r][cs + i*4 + 0] = (bf16)f.x;
                T[r][cs + i*4 + 1] = (bf16)f.y;
                T[r][cs + i*4 + 2] = (bf16)f.z;
                T[r][cs + i*4 + 3] = (bf16)f.w;
            }
        }
        __syncthreads();
        {
            const int ss = tid >> 2, ks = (tid & 3) << 4;
            bf16x8 a, b8;
            #pragma unroll
            for (int j = 0; j < 8; ++j) { a[j] = T[ks + j][ss]; b8[j] = T[ks + 8 + j][ss]; }
            bf16* dp = img_bf + ((size_t)b * HW + s0 + ss) * CCH + c0 + ks;
            *(bf16x8*)dp = a;
            *(bf16x8*)(dp + 8) = b8;
        }
    } else {
        if (blockIdx.x >= 8) return;
        const int w = z - 16;
        const float* src = (w == 0) ? Wq : (w == 1) ? Wk : (w == 2) ? Wv : Wo;
        const int n0 = blockIdx.x * 64, k0 = blockIdx.y * 64;
        {
            const int r = tid >> 2, cs = (tid & 3) << 4;
            const float* sp = src + (size_t)(k0 + r) * CCH + n0 + cs;
            #pragma unroll
            for (int i = 0; i < 4; ++i) {
                float4 f = *(const float4*)(sp + i * 4);
                T[r][cs + i*4 + 0] = (bf16)f.x;
                T[r][cs + i*4 + 1] = (bf16)f.y;
                T[r][cs + i*4 + 2] = (bf16)f.z;
                T[r][cs + i*4 + 3] = (bf16)f.w;
            }
        }
        __syncthreads();
        {
            const int nn = tid >> 2, ks = (tid & 3) << 4;
            bf16x8 a, b8;
            #pragma unroll
            for (int j = 0; j < 8; ++j) { a[j] = T[ks + j][nn]; b8[j] = T[ks + 8 + j][nn]; }
            bf16* dp = wT + (size_t)w * CCH * CCH + (size_t)(n0 + nn) * CCH + k0 + ks;
            *(bf16x8*)dp = a;
            *(bf16x8*)(dp + 8) = b8;
        }
    }
}

// ---------------------------------------------------------------------------
// Merged projection GEMMs. Blocks 0..511: Q (img_bf @ WqT, Ct-orientation,
// bf16x4 stores). Blocks 512..767: K|V (raw f32 audio cast in staging;
// K row-major per head, V transposed per head).
// ---------------------------------------------------------------------------
__global__ __launch_bounds__(256) void gemm_qkv(
    const bf16* __restrict__ img_bf, const float* __restrict__ audio,
    const bf16* __restrict__ wT,
    const float* __restrict__ bq, const float* __restrict__ bk,
    const float* __restrict__ bv,
    bf16* __restrict__ q_bf, bf16* __restrict__ khout, bf16* __restrict__ vtout)
{
    const int bid = blockIdx.x;
    const int tid = threadIdx.x;
    const int wave = tid >> 6, lane = tid & 63;
    const int l15 = lane & 15, quad = lane >> 4;
    const int wm = (wave >> 1) * 64, wn = (wave & 1) * 64;
    const int r16 = lane >> 2;
    const int ks  = (lane & 3) * 8;

    __shared__ bf16 As[128 * 32];
    __shared__ bf16 Bs[128 * 32];

    f32x4 acc[4][4];
    #pragma unroll
    for (int i = 0; i < 4; ++i)
        #pragma unroll
        for (int j = 0; j < 4; ++j)
            acc[i][j] = (f32x4){0.f, 0.f, 0.f, 0.f};

    if (bid < 512) {
        const int m0 = (bid >> 2) * 128, n0 = (bid & 3) * 128;
        for (int k0 = 0; k0 < 512; k0 += 32) {
            #pragma unroll
            for (int i = 0; i < 2; ++i) {
                const int c = wave * 2 + i;
                gl_lds16(img_bf + (size_t)(m0 + c * 16 + r16) * 512 + k0 + ks, &As[c * 512]);
                gl_lds16(wT     + (size_t)(n0 + c * 16 + r16) * 512 + k0 + ks, &Bs[c * 512]);
            }
            __syncthreads();
            bf16x8 af[4], bfr[4];
            #pragma unroll
            for (int i = 0; i < 4; ++i)
                af[i] = *(const bf16x8*)&As[(wm + i * 16 + l15) * 32 + quad * 8];
            #pragma unroll
            for (int j = 0; j < 4; ++j)
                bfr[j] = *(const bf16x8*)&Bs[(wn + j * 16 + l15) * 32 + quad * 8];
            #pragma unroll
            for (int i = 0; i < 4; ++i)
                #pragma unroll
                for (int j = 0; j < 4; ++j)
                    acc[i][j] = __builtin_amdgcn_mfma_f32_16x16x32_bf16(bfr[j], af[i], acc[i][j], 0, 0, 0);
            __syncthreads();
        }
        #pragma unroll
        for (int j = 0; j < 4; ++j) {
            const int gn = n0 + wn + j * 16 + quad * 4;
            const f32x4 bv4 = *(const f32x4*)(bq + gn);
            #pragma unroll
            for (int i = 0; i < 4; ++i) {
                const int gm = m0 + wm + i * 16 + l15;
                bf16x4 ov;
                #pragma unroll
                for (int r = 0; r < 4; ++r) ov[r] = (bf16)(acc[i][j][r] + bv4[r]);
                *(bf16x4*)(q_bf + (size_t)gm * 512 + gn) = ov;
            }
        }
    } else {
        const int t = bid - 512;
        const int m0 = (t >> 3) * 128, n0 = (t & 7) * 128;
        const bf16* Bt = wT + 262144;   // Wk^T rows 0..511, Wv^T rows 512..1023
        for (int k0 = 0; k0 < 512; k0 += 32) {
            #pragma unroll
            for (int i = 0; i < 2; ++i) {
                const int c = wave * 2 + i;
                gl_lds16(Bt + (size_t)(n0 + c * 16 + r16) * 512 + k0 + ks, &Bs[c * 512]);
            }
            #pragma unroll
            for (int i = 0; i < 2; ++i) {
                const int u = tid + (i << 8);
                const int r = u >> 2, seg = (u & 3) << 3;
                const float* ap = audio + (size_t)(m0 + r) * 512 + k0 + seg;
                f32x4 a0 = *(const f32x4*)ap;
                f32x4 a1 = *(const f32x4*)(ap + 4);
                bf16x8 o;
                #pragma unroll
                for (int qq = 0; qq < 4; ++qq) { o[qq] = (bf16)a0[qq]; o[qq + 4] = (bf16)a1[qq]; }
                *(bf16x8*)&As[r * 32 + seg] = o;
            }
            __syncthreads();
            bf16x8 af[4], bfr[4];
            #pragma unroll
            for (int i = 0; i < 4; ++i)
                af[i] = *(const bf16x8*)&As[(wm + i * 16 + l15) * 32 + quad * 8];
            #pragma unroll
            for (int j = 0; j < 4; ++j)
                bfr[j] = *(const bf16x8*)&Bs[(wn + j * 16 + l15) * 32 + quad * 8];
            #pragma unroll
            for (int i = 0; i < 4; ++i)
                #pragma unroll
                for (int j = 0; j < 4; ++j)
                    acc[i][j] = __builtin_amdgcn_mfma_f32_16x16x32_bf16(af[i], bfr[j], acc[i][j], 0, 0, 0);
            __syncthreads();
        }
        #pragma unroll
        for (int j = 0; j < 4; ++j) {
            const int gn = n0 + wn + j * 16 + l15;
            if (gn < 512) {
                const int h = gn >> 6, d = gn & 63;
                const float bias = bk[gn];
                #pragma unroll
                for (int i = 0; i < 4; ++i) {
                    const int gm = m0 + wm + i * 16 + quad * 4;
                    const int b = gm >> 8, key = gm & 255;
                    bf16* base = khout + ((((size_t)b * N_HEADS + h) * K_LEN) + key) * 64 + d;
                    #pragma unroll
                    for (int r = 0; r < 4; ++r)
                        base[(size_t)r * 64] = (bf16)(acc[i][j][r] + bias);
                }
            } else {
                const int ch = gn - 512;
                const int h = ch >> 6, d = ch & 63;
                const float bias = bv[ch];
                #pragma unroll
                for (int i = 0; i < 4; ++i) {
                    const int gm = m0 + wm + i * 16 + quad * 4;
                    const int b = gm >> 8, key = gm & 255;
                    bf16x4 pk;
                    #pragma unroll
                    for (int r = 0; r < 4; ++r) pk[r] = (bf16)(acc[i][j][r] + bias);
                    *(bf16x4*)(vtout + (((size_t)b * N_HEADS + h) * 64 + d) * K_LEN + key) = pk;
                }
            }
        }
    }
}

// ---------------------------------------------------------------------------
// MFMA attention v2: K fragments in VGPRs (no phase-1 LDS), Pt in its own
// LDS region (wave-private -> barrier-free steady state), s0-loop x4 per
// block amortizes Vs staging + K loads. Grid (128 bh, 4 sg), 2 blocks/CU.
// ---------------------------------------------------------------------------
__global__ __launch_bounds__(256, 2) void attn_mfma(
    const bf16* __restrict__ q,    // [B*1024][512]
    const bf16* __restrict__ kh,   // [B][H][256][64]
    const bf16* __restrict__ vt,   // [B][H][64][256]
    bf16* __restrict__ o)          // [B*1024][512]
{
    const int bh = blockIdx.x;
    const int sg = blockIdx.y;
    const int tid = threadIdx.x;
    const int wave = tid >> 6, lane = tid & 63;
    const int l15 = lane & 15, quad = lane >> 4;
    const int b = bh >> 3, h = bh & 7;

    __shared__ bf16 Vs[64 * 264];       // 33792 B
    __shared__ bf16 Pt[4 * 16 * 264];   // 33792 B, per-wave [16][264]

    const bf16* khb = kh + (size_t)bh * K_LEN * 64;
    const bf16* vtb = vt + (size_t)bh * 64 * K_LEN;

    // Stage V^T once
    #pragma unroll
    for (int i = 0; i < 8; ++i) {
        const int chunk = tid + (i << 8);
        const int d = chunk >> 5, kseg = (chunk & 31) << 3;
        *(bf16x8*)&Vs[d * 264 + kseg] = *(const bf16x8*)(vtb + d * 256 + kseg);
    }
    // K fragments in registers (A-operand layout for S^T = K @ Q^T)
    bf16x8 kf0[16], kf1[16];
    #pragma unroll
    for (int m = 0; m < 16; ++m) {
        const bf16* kp = khb + (size_t)(m * 16 + l15) * 64 + quad * 8;
        kf0[m] = *(const bf16x8*)kp;
        kf1[m] = *(const bf16x8*)(kp + 32);
    }
    __syncthreads();

    bf16* PtW = &Pt[wave * 4224];

    for (int it = 0; it < 4; ++it) {
        const int qrow = sg * 256 + it * 64 + wave * 16 + l15;
        const bf16* qp = q + ((size_t)(b * HW + qrow)) * 512 + h * 64 + quad * 8;
        const bf16x8 qf0 = *(const bf16x8*)qp;
        const bf16x8 qf1 = *(const bf16x8*)(qp + 32);

        // Phase 1: S^T, all operands in registers
        f32x4 acc[16];
        #pragma unroll
        for (int m = 0; m < 16; ++m) acc[m] = (f32x4){0.f, 0.f, 0.f, 0.f};
        #pragma unroll
        for (int m = 0; m < 16; ++m) {
            acc[m] = __builtin_amdgcn_mfma_f32_16x16x32_bf16(kf0[m], qf0, acc[m], 0, 0, 0);
            acc[m] = __builtin_amdgcn_mfma_f32_16x16x32_bf16(kf1[m], qf1, acc[m], 0, 0, 0);
        }

        // Phase 2: exact softmax over 256 keys (reduce across quads)
        float mx = -1e30f;
        #pragma unroll
        for (int m = 0; m < 16; ++m)
            mx = fmaxf(mx, fmaxf(fmaxf(acc[m][0], acc[m][1]), fmaxf(acc[m][2], acc[m][3])));
        mx = fmaxf(mx, __shfl_xor(mx, 16, 64));
        mx = fmaxf(mx, __shfl_xor(mx, 32, 64));

        float l_sum = 0.f;
        #pragma unroll
        for (int m = 0; m < 16; ++m) {
            bf16x4 pk;
            #pragma unroll
            for (int r = 0; r < 4; ++r) {
                const float p = __expf((acc[m][r] - mx) * 0.125f);
                l_sum += p;
                pk[r] = (bf16)p;
            }
            *(bf16x4*)&PtW[l15 * 264 + m * 16 + quad * 4] = pk;
        }
        l_sum += __shfl_xor(l_sum, 16, 64);
        l_sum += __shfl_xor(l_sum, 32, 64);
        // no barrier: PtW is wave-private, Vs read-only

        // Phase 3: out^T = Vt @ Pt
        f32x4 oacc[4];
        #pragma unroll
        for (int m = 0; m < 4; ++m) oacc[m] = (f32x4){0.f, 0.f, 0.f, 0.f};
        #pragma unroll
        for (int s = 0; s < 8; ++s) {
            const bf16x8 pb = *(const bf16x8*)&PtW[l15 * 264 + s * 32 + quad * 8];
            #pragma unroll
            for (int m = 0; m < 4; ++m) {
                const bf16x8 va = *(const bf16x8*)&Vs[(m * 16 + l15) * 264 + s * 32 + quad * 8];
                oacc[m] = __builtin_amdgcn_mfma_f32_16x16x32_bf16(va, pb, oacc[m], 0, 0, 0);
            }
        }

        const float inv = 1.0f / l_sum;
        bf16* op = o + ((size_t)(b * HW + qrow)) * 512 + h * 64 + quad * 4;
        #pragma unroll
        for (int m = 0; m < 4; ++m) {
            bf16x4 ov;
            #pragma unroll
            for (int r = 0; r < 4; ++r) ov[r] = (bf16)(oacc[m][r] * inv);
            *(bf16x4*)&op[m * 16] = ov;
        }
    }
}

// ---------------------------------------------------------------------------
// Fused out-projection + bias + residual + LayerNorm + transposed store.
// 256 thr (4 waves), 32 s-rows x full N=512, grid 512 (2/CU).
// Orientation mfma(bfr, af): lane&15 = s, quad*4+reg = c ->
//   residual from img_bf as vector bf16x4 along c; stats per-s via shfl+LDS;
//   output: 64 coalesced scalar f32 stores (64B/quad segments).
// ---------------------------------------------------------------------------
__global__ __launch_bounds__(256) void gemm_oln(
    const bf16* __restrict__ A,      // attn out [B*1024][512]
    const bf16* __restrict__ Wt,     // Wo^T [512][512]
    const float* __restrict__ bo,
    const bf16* __restrict__ imgb,   // residual [B*1024][512] bf16
    const float* __restrict__ gamma, const float* __restrict__ beta,
    float* __restrict__ out)         // [B][512][1024]
{
    const int tid  = threadIdx.x;
    const int wave = tid >> 6, lane = tid & 63;
    const int l15 = lane & 15, quad = lane >> 4;
    const int m0 = blockIdx.x * 32;
    const int b  = m0 >> 10, s0 = m0 & 1023;
    const int wn = wave * 128;

    __shared__ bf16 As[32 * 32];
    __shared__ bf16 Bs[512 * 32];
    __shared__ float redS[2][32][4];

    const int r16 = lane >> 2;
    const int ks  = (lane & 3) * 8;

    f32x4 acc[2][8];
    #pragma unroll
    for (int i = 0; i < 2; ++i)
        #pragma unroll
        for (int j = 0; j < 8; ++j)
            acc[i][j] = (f32x4){0.f, 0.f, 0.f, 0.f};

    for (int k0 = 0; k0 < 512; k0 += 32) {
        #pragma unroll
        for (int t = 0; t < 8; ++t) {
            const int cb = wave * 8 + t;
            gl_lds16(Wt + (size_t)(cb * 16 + r16) * 512 + k0 + ks, &Bs[cb * 512]);
        }
        if (wave < 2)
            gl_lds16(A + (size_t)(m0 + wave * 16 + r16) * 512 + k0 + ks, &As[wave * 512]);
        __syncthreads();
        bf16x8 af[2], bfr[8];
        #pragma unroll
        for (int i = 0; i < 2; ++i)
            af[i] = *(const bf16x8*)&As[(i * 16 + l15) * 32 + quad * 8];
        #pragma unroll
        for (int j = 0; j < 8; ++j)
            bfr[j] = *(const bf16x8*)&Bs[(wn + j * 16 + l15) * 32 + quad * 8];
        #pragma unroll
        for (int i = 0; i < 2; ++i)
            #pragma unroll
            for (int j = 0; j < 8; ++j)
                acc[i][j] = __builtin_amdgcn_mfma_f32_16x16x32_bf16(bfr[j], af[i], acc[i][j], 0, 0, 0);
        __syncthreads();
    }

    // y = acc + bo + residual (bf16x4 vector loads); per-s partial stats
    float rs_[2] = {0.f, 0.f}, rq_[2] = {0.f, 0.f};
    #pragma unroll
    for (int j = 0; j < 8; ++j) {
        const int c4 = wn + j * 16 + quad * 4;
        const f32x4 bo4 = *(const f32x4*)(bo + c4);
        #pragma unroll
        for (int i = 0; i < 2; ++i) {
            const bf16x4 res = *(const bf16x4*)(imgb + (size_t)(m0 + i * 16 + l15) * 512 + c4);
            #pragma unroll
            for (int r = 0; r < 4; ++r) {
                const float y = acc[i][j][r] + bo4[r] + (float)res[r];
                acc[i][j][r] = y;
                rs_[i] += y;
                rq_[i] += y * y;
            }
        }
    }
    #pragma unroll
    for (int i = 0; i < 2; ++i) {
        rs_[i] += __shfl_xor(rs_[i], 16, 64);
        rs_[i] += __shfl_xor(rs_[i], 32, 64);
        rq_[i] += __shfl_xor(rq_[i], 16, 64);
        rq_[i] += __shfl_xor(rq_[i], 32, 64);
    }
    if (quad == 0) {
        #pragma unroll
        for (int i = 0; i < 2; ++i) {
            redS[0][i * 16 + l15][wave] = rs_[i];
            redS[1][i * 16 + l15][wave] = rq_[i];
        }
    }
    __syncthreads();

    float mu[2], rstd[2];
    #pragma unroll
    for (int i = 0; i < 2; ++i) {
        const int s = i * 16 + l15;
        const float sm = redS[0][s][0] + redS[0][s][1] + redS[0][s][2] + redS[0][s][3];
        const float sq = redS[1][s][0] + redS[1][s][1] + redS[1][s][2] + redS[1][s][3];
        mu[i] = sm * (1.f / 512.f);
        rstd[i] = rsqrtf(sq * (1.f / 512.f) - mu[i] * mu[i] + EPS);
    }

    // normalize + direct stores to out[b][c][s]
    #pragma unroll
    for (int j = 0; j < 8; ++j) {
        const int c4 = wn + j * 16 + quad * 4;
        const f32x4 g4 = *(const f32x4*)(gamma + c4);
        const f32x4 b4 = *(const f32x4*)(beta + c4);
        #pragma unroll
        for (int i = 0; i < 2; ++i) {
            #pragma unroll
            for (int r = 0; r < 4; ++r) {
                const float z = (acc[i][j][r] - mu[i]) * rstd[i] * g4[r] + b4[r];
                out[((size_t)b * CCH + c4 + r) * HW + s0 + i * 16 + l15] = z;
            }
        }
    }
}

// ---------------------------------------------------------------------------
extern "C" void kernel_launch(void* const* d_in, const int* in_sizes, int n_in,
                              void* d_out, int out_size, void* d_ws, size_t ws_size,
                              hipStream_t stream) {
    const float* img   = (const float*)d_in[0];
    const float* audio = (const float*)d_in[1];
    const float* Wq    = (const float*)d_in[2];
    const float* bq    = (const float*)d_in[3];
    const float* Wk    = (const float*)d_in[4];
    const float* bk    = (const float*)d_in[5];
    const float* Wv    = (const float*)d_in[6];
    const float* bv    = (const float*)d_in[7];
    const float* Wo    = (const float*)d_in[8];
    const float* bo    = (const float*)d_in[9];
    const float* gamma = (const float*)d_in[10];
    const float* beta  = (const float*)d_in[11];

    bf16* wsb    = (bf16*)d_ws;
    bf16* img_bf = wsb;                     // 8388608
    bf16* wT     = img_bf + 8388608;        // 4*262144 (q,k,v,o)
    bf16* q_bf   = wT + 1048576;            // 8388608
    bf16* kh_bf  = q_bf + 8388608;          // 2097152  [B][H][256][64]
    bf16* vt_bf  = kh_bf + 2097152;         // 2097152  [B][H][64][256]
    bf16* a_bf   = vt_bf + 2097152;         // 8388608

    // 1) transposes/casts (img + 4 weights)
    tc_all<<<dim3(16, 8, 20), 256, 0, stream>>>(img, Wq, Wk, Wv, Wo, img_bf, wT);
    // 2) Q + K|V projections in one launch
    gemm_qkv<<<dim3(768), 256, 0, stream>>>(img_bf, audio, wT, bq, bk, bv,
                                            q_bf, kh_bf, vt_bf);
    // 3) attention (K in regs, barrier-free loop)
    attn_mfma<<<dim3(B_SZ * N_HEADS, 4), 256, 0, stream>>>(q_bf, kh_bf, vt_bf, a_bf);
    // 4) out-projection + residual + LayerNorm + store
    gemm_oln<<<dim3(512), 256, 0, stream>>>(a_bf, wT + 3 * 262144, bo, img_bf,
                                            gamma, beta, (float*)d_out);
}

// Round 8
// 203.637 us; speedup vs baseline: 1.1000x; 1.1000x over previous
//
#include <hip/hip_runtime.h>
#include <cstddef>

#define B_SZ 16
#define HW 1024
#define CCH 512
#define K_LEN 256
#define N_HEADS 8
#define EPS 1e-5f

typedef __bf16 bf16;
typedef bf16 bf16x8 __attribute__((ext_vector_type(8)));
typedef bf16 bf16x4 __attribute__((ext_vector_type(4)));
typedef float f32x4 __attribute__((ext_vector_type(4)));

// async global->LDS, 16B per lane; LDS dest is wave-uniform base + lane*16
__device__ __forceinline__ void gl_lds16(const bf16* g, bf16* l) {
    __builtin_amdgcn_global_load_lds(
        (const __attribute__((address_space(1))) void*)g,
        (__attribute__((address_space(3))) void*)l, 16, 0, 0);
}

// ---------------------------------------------------------------------------
// Transpose+cast weights: W[k][n] f32 -> Wt[n][k] bf16, packed [4][512][512]
// ---------------------------------------------------------------------------
__global__ __launch_bounds__(256) void tc_w(
    const float* __restrict__ Wq, const float* __restrict__ Wk,
    const float* __restrict__ Wv, const float* __restrict__ Wo,
    bf16* __restrict__ dst)
{
    const int w = blockIdx.z;
    const float* src = (w == 0) ? Wq : (w == 1) ? Wk : (w == 2) ? Wv : Wo;
    const int n0 = blockIdx.x * 64;
    const int k0 = blockIdx.y * 64;
    __shared__ bf16 T[64][72];
    const int tid = threadIdx.x;
    {
        const int r = tid >> 2, cs = (tid & 3) << 4;
        const float* sp = src + (size_t)(k0 + r) * CCH + n0 + cs;
        #pragma unroll
        for (int i = 0; i < 4; ++i) {
            float4 f = *(const float4*)(sp + i * 4);
            T[r][cs + i*4 + 0] = (bf16)f.x;
            T[r][cs + i*4 + 1] = (bf16)f.y;
            T[r][cs + i*4 + 2] = (bf16)f.z;
            T[r][cs + i*4 + 3] = (bf16)f.w;
        }
    }
    __syncthreads();
    {
        const int nn = tid >> 2, ks = (tid & 3) << 4;
        bf16x8 a, b8;
        #pragma unroll
        for (int j = 0; j < 8; ++j) { a[j] = T[ks + j][nn]; b8[j] = T[ks + 8 + j][nn]; }
        bf16* dp = dst + (size_t)w * CCH * CCH + (size_t)(n0 + nn) * CCH + k0 + ks;
        *(bf16x8*)dp = a;
        *(bf16x8*)(dp + 8) = b8;
    }
}

// ---------------------------------------------------------------------------
// Merged projection GEMMs.
// Blocks 0..511: Q = img_seq @ WqT. A-staging reads RAW f32 img[b][c][s] and
//   transposes+casts into As (stride 40, b128 writes, conflict-free).
// Blocks 512..767: K|V (raw f32 audio cast in staging; K row-major per head,
//   V transposed per head).
// ---------------------------------------------------------------------------
__global__ __launch_bounds__(256) void gemm_qkv(
    const float* __restrict__ img, const float* __restrict__ audio,
    const bf16* __restrict__ wT,
    const float* __restrict__ bq, const float* __restrict__ bk,
    const float* __restrict__ bv,
    bf16* __restrict__ q_bf, bf16* __restrict__ khout, bf16* __restrict__ vtout)
{
    const int bid = blockIdx.x;
    const int tid = threadIdx.x;
    const int wave = tid >> 6, lane = tid & 63;
    const int l15 = lane & 15, quad = lane >> 4;
    const int wm = (wave >> 1) * 64, wn = (wave & 1) * 64;
    const int r16 = lane >> 2;
    const int ks  = (lane & 3) * 8;

    __shared__ bf16 As[128 * 40];
    __shared__ bf16 Bs[128 * 32];

    f32x4 acc[4][4];
    #pragma unroll
    for (int i = 0; i < 4; ++i)
        #pragma unroll
        for (int j = 0; j < 4; ++j)
            acc[i][j] = (f32x4){0.f, 0.f, 0.f, 0.f};

    if (bid < 512) {
        const int m0 = (bid >> 2) * 128, n0 = (bid & 3) * 128;
        const int bi = m0 >> 10, s0 = m0 & 1023;
        const int srow = tid >> 1;            // 0..127
        const int oc   = (tid & 1) * 16;      // c-offset 0 or 16
        for (int k0 = 0; k0 < 512; k0 += 32) {
            // B via async 16B staging (wT row-major [n][k])
            #pragma unroll
            for (int i = 0; i < 2; ++i) {
                const int c = wave * 2 + i;
                gl_lds16(wT + (size_t)(n0 + c * 16 + r16) * 512 + k0 + ks, &Bs[c * 512]);
            }
            // A: transpose+cast raw img tile c[k0,k0+32) x s[s0+0,128)
            #pragma unroll
            for (int g = 0; g < 2; ++g) {
                const int c = oc + g * 8;
                const float* ip = img + ((size_t)bi * CCH + k0 + c) * HW + s0 + srow;
                bf16x8 v;
                #pragma unroll
                for (int j = 0; j < 8; ++j)
                    v[j] = (bf16)ip[(size_t)j * HW];
                *(bf16x8*)&As[srow * 40 + c] = v;
            }
            __syncthreads();
            bf16x8 af[4], bfr[4];
            #pragma unroll
            for (int i = 0; i < 4; ++i)
                af[i] = *(const bf16x8*)&As[(wm + i * 16 + l15) * 40 + quad * 8];
            #pragma unroll
            for (int j = 0; j < 4; ++j)
                bfr[j] = *(const bf16x8*)&Bs[(wn + j * 16 + l15) * 32 + quad * 8];
            #pragma unroll
            for (int i = 0; i < 4; ++i)
                #pragma unroll
                for (int j = 0; j < 4; ++j)
                    acc[i][j] = __builtin_amdgcn_mfma_f32_16x16x32_bf16(bfr[j], af[i], acc[i][j], 0, 0, 0);
            __syncthreads();
        }
        // Ct orientation: lane&15 = m, quad*4+reg = n -> 8B bf16x4 stores
        #pragma unroll
        for (int j = 0; j < 4; ++j) {
            const int gn = n0 + wn + j * 16 + quad * 4;
            const f32x4 bv4 = *(const f32x4*)(bq + gn);
            #pragma unroll
            for (int i = 0; i < 4; ++i) {
                const int gm = m0 + wm + i * 16 + l15;
                bf16x4 ov;
                #pragma unroll
                for (int r = 0; r < 4; ++r) ov[r] = (bf16)(acc[i][j][r] + bv4[r]);
                *(bf16x4*)(q_bf + (size_t)gm * 512 + gn) = ov;
            }
        }
    } else {
        const int t = bid - 512;
        const int m0 = (t >> 3) * 128, n0 = (t & 7) * 128;
        const bf16* Bt = wT + 262144;   // Wk^T rows 0..511, Wv^T rows 512..1023
        for (int k0 = 0; k0 < 512; k0 += 32) {
            #pragma unroll
            for (int i = 0; i < 2; ++i) {
                const int c = wave * 2 + i;
                gl_lds16(Bt + (size_t)(n0 + c * 16 + r16) * 512 + k0 + ks, &Bs[c * 512]);
            }
            #pragma unroll
            for (int i = 0; i < 2; ++i) {
                const int u = tid + (i << 8);
                const int r = u >> 2, seg = (u & 3) << 3;
                const float* ap = audio + (size_t)(m0 + r) * 512 + k0 + seg;
                f32x4 a0 = *(const f32x4*)ap;
                f32x4 a1 = *(const f32x4*)(ap + 4);
                bf16x8 o;
                #pragma unroll
                for (int qq = 0; qq < 4; ++qq) { o[qq] = (bf16)a0[qq]; o[qq + 4] = (bf16)a1[qq]; }
                *(bf16x8*)&As[r * 40 + seg] = o;
            }
            __syncthreads();
            bf16x8 af[4], bfr[4];
            #pragma unroll
            for (int i = 0; i < 4; ++i)
                af[i] = *(const bf16x8*)&As[(wm + i * 16 + l15) * 40 + quad * 8];
            #pragma unroll
            for (int j = 0; j < 4; ++j)
                bfr[j] = *(const bf16x8*)&Bs[(wn + j * 16 + l15) * 32 + quad * 8];
            #pragma unroll
            for (int i = 0; i < 4; ++i)
                #pragma unroll
                for (int j = 0; j < 4; ++j)
                    acc[i][j] = __builtin_amdgcn_mfma_f32_16x16x32_bf16(af[i], bfr[j], acc[i][j], 0, 0, 0);
            __syncthreads();
        }
        #pragma unroll
        for (int j = 0; j < 4; ++j) {
            const int gn = n0 + wn + j * 16 + l15;
            if (gn < 512) {
                const int h = gn >> 6, d = gn & 63;
                const float bias = bk[gn];
                #pragma unroll
                for (int i = 0; i < 4; ++i) {
                    const int gm = m0 + wm + i * 16 + quad * 4;
                    const int b = gm >> 8, key = gm & 255;
                    bf16* base = khout + ((((size_t)b * N_HEADS + h) * K_LEN) + key) * 64 + d;
                    #pragma unroll
                    for (int r = 0; r < 4; ++r)
                        base[(size_t)r * 64] = (bf16)(acc[i][j][r] + bias);
                }
            } else {
                const int ch = gn - 512;
                const int h = ch >> 6, d = ch & 63;
                const float bias = bv[ch];
                #pragma unroll
                for (int i = 0; i < 4; ++i) {
                    const int gm = m0 + wm + i * 16 + quad * 4;
                    const int b = gm >> 8, key = gm & 255;
                    bf16x4 pk;
                    #pragma unroll
                    for (int r = 0; r < 4; ++r) pk[r] = (bf16)(acc[i][j][r] + bias);
                    *(bf16x4*)(vtout + (((size_t)b * N_HEADS + h) * 64 + d) * K_LEN + key) = pk;
                }
            }
        }
    }
}

// ---------------------------------------------------------------------------
// MFMA attention (R3 proven design): S^T trick + exact softmax + Vt@Pt.
// ---------------------------------------------------------------------------
__global__ __launch_bounds__(256) void attn_mfma(
    const bf16* __restrict__ q,    // [B*1024][512]
    const bf16* __restrict__ kh,   // [B][H][256][64]
    const bf16* __restrict__ vt,   // [B][H][64][256]
    bf16* __restrict__ o)          // [B*1024][512]
{
    const int bh = blockIdx.x;
    const int s0 = blockIdx.y * 64;
    const int tid = threadIdx.x;
    const int wave = tid >> 6, lane = tid & 63;
    const int l15 = lane & 15, quad = lane >> 4;
    const int b = bh >> 3, h = bh & 7;

    __shared__ bf16 KsPt[18432];   // Ks [256][72]; later Pt: 4 waves x [16][264]
    __shared__ bf16 Vs[16896];     // Vt [64][264]

    const bf16* khb = kh + (size_t)bh * K_LEN * 64;
    const bf16* vtb = vt + (size_t)bh * 64 * K_LEN;

    #pragma unroll
    for (int i = 0; i < 8; ++i) {
        const int chunk = tid + (i << 8);
        const int key = chunk >> 3, dseg = (chunk & 7) << 3;
        *(bf16x8*)&KsPt[key * 72 + dseg] = *(const bf16x8*)(khb + key * 64 + dseg);
        const int d = chunk >> 5, kseg = (chunk & 31) << 3;
        *(bf16x8*)&Vs[d * 264 + kseg] = *(const bf16x8*)(vtb + d * 256 + kseg);
    }
    __syncthreads();

    const int qrow = s0 + wave * 16 + l15;
    const bf16* qp = q + ((size_t)(b * HW + qrow)) * 512 + h * 64 + quad * 8;
    const bf16x8 qf0 = *(const bf16x8*)qp;
    const bf16x8 qf1 = *(const bf16x8*)(qp + 32);

    f32x4 acc[16];
    #pragma unroll
    for (int m = 0; m < 16; ++m) acc[m] = (f32x4){0.f, 0.f, 0.f, 0.f};
    #pragma unroll
    for (int m = 0; m < 16; ++m) {
        const bf16x8 a0 = *(const bf16x8*)&KsPt[(m * 16 + l15) * 72 + quad * 8];
        const bf16x8 a1 = *(const bf16x8*)&KsPt[(m * 16 + l15) * 72 + 32 + quad * 8];
        acc[m] = __builtin_amdgcn_mfma_f32_16x16x32_bf16(a0, qf0, acc[m], 0, 0, 0);
        acc[m] = __builtin_amdgcn_mfma_f32_16x16x32_bf16(a1, qf1, acc[m], 0, 0, 0);
    }

    float mx = -1e30f;
    #pragma unroll
    for (int m = 0; m < 16; ++m)
        mx = fmaxf(mx, fmaxf(fmaxf(acc[m][0], acc[m][1]), fmaxf(acc[m][2], acc[m][3])));
    mx = fmaxf(mx, __shfl_xor(mx, 16, 64));
    mx = fmaxf(mx, __shfl_xor(mx, 32, 64));

    __syncthreads();   // all waves done with Ks; overlay Pt

    bf16* PtW = &KsPt[wave * 4224];
    float l_sum = 0.f;
    #pragma unroll
    for (int m = 0; m < 16; ++m) {
        bf16x4 pk;
        #pragma unroll
        for (int r = 0; r < 4; ++r) {
            const float p = __expf((acc[m][r] - mx) * 0.125f);
            l_sum += p;
            pk[r] = (bf16)p;
        }
        *(bf16x4*)&PtW[l15 * 264 + m * 16 + quad * 4] = pk;
    }
    l_sum += __shfl_xor(l_sum, 16, 64);
    l_sum += __shfl_xor(l_sum, 32, 64);
    __syncthreads();

    f32x4 oacc[4];
    #pragma unroll
    for (int m = 0; m < 4; ++m) oacc[m] = (f32x4){0.f, 0.f, 0.f, 0.f};
    #pragma unroll
    for (int s = 0; s < 8; ++s) {
        const bf16x8 pb = *(const bf16x8*)&PtW[l15 * 264 + s * 32 + quad * 8];
        #pragma unroll
        for (int m = 0; m < 4; ++m) {
            const bf16x8 va = *(const bf16x8*)&Vs[(m * 16 + l15) * 264 + s * 32 + quad * 8];
            oacc[m] = __builtin_amdgcn_mfma_f32_16x16x32_bf16(va, pb, oacc[m], 0, 0, 0);
        }
    }

    const float inv = 1.0f / l_sum;
    bf16* op = o + ((size_t)(b * HW + qrow)) * 512 + h * 64 + quad * 4;
    #pragma unroll
    for (int m = 0; m < 4; ++m) {
        bf16x4 ov;
        #pragma unroll
        for (int r = 0; r < 4; ++r) ov[r] = (bf16)(oacc[m][r] * inv);
        *(bf16x4*)&op[m * 16] = ov;
    }
}

// ---------------------------------------------------------------------------
// Fused out-projection + bias + residual + LayerNorm + transposed store
// (R6 orientation). 256 thr (4 waves), 32 s-rows x full N=512, grid 512.
// mfma(af, bfr): lane&15 = c-chunk, quad*4+reg = s -> residual f32x4 along s
// from raw img; f32x4 stores to out[b][c][s].
// ---------------------------------------------------------------------------
__global__ __launch_bounds__(256) void gemm_oln(
    const bf16* __restrict__ A,      // attn out [B*1024][512]
    const bf16* __restrict__ Wt,     // Wo^T [512][512]
    const float* __restrict__ bo,
    const float* __restrict__ img,   // raw residual [B][512][1024] f32
    const float* __restrict__ gamma, const float* __restrict__ beta,
    float* __restrict__ out)         // [B][512][1024]
{
    const int tid  = threadIdx.x;
    const int wave = tid >> 6, lane = tid & 63;
    const int l15 = lane & 15, quad = lane >> 4;
    const int m0 = blockIdx.x * 32;
    const int b  = m0 >> 10, s0 = m0 & 1023;
    const int wn = wave * 128;

    __shared__ bf16 As[32 * 32];
    __shared__ bf16 Bs[512 * 32];
    __shared__ float redS[2][32][4];   // [sum|sq][s][wave]

    const int r16 = lane >> 2;
    const int ks  = (lane & 3) * 8;

    f32x4 acc[2][8];
    #pragma unroll
    for (int i = 0; i < 2; ++i)
        #pragma unroll
        for (int j = 0; j < 8; ++j)
            acc[i][j] = (f32x4){0.f, 0.f, 0.f, 0.f};

    for (int k0 = 0; k0 < 512; k0 += 32) {
        #pragma unroll
        for (int t = 0; t < 8; ++t) {
            const int cb = wave * 8 + t;
            gl_lds16(Wt + (size_t)(cb * 16 + r16) * 512 + k0 + ks, &Bs[cb * 512]);
        }
        if (wave < 2)
            gl_lds16(A + (size_t)(m0 + wave * 16 + r16) * 512 + k0 + ks, &As[wave * 512]);
        __syncthreads();
        bf16x8 af[2], bfr[8];
        #pragma unroll
        for (int i = 0; i < 2; ++i)
            af[i] = *(const bf16x8*)&As[(i * 16 + l15) * 32 + quad * 8];
        #pragma unroll
        for (int j = 0; j < 8; ++j)
            bfr[j] = *(const bf16x8*)&Bs[(wn + j * 16 + l15) * 32 + quad * 8];
        #pragma unroll
        for (int i = 0; i < 2; ++i)
            #pragma unroll
            for (int j = 0; j < 8; ++j)
                acc[i][j] = __builtin_amdgcn_mfma_f32_16x16x32_bf16(af[i], bfr[j], acc[i][j], 0, 0, 0);
        __syncthreads();
    }

    // Pass 1: y = acc + bo + residual (f32x4 along s); per-s partial stats
    float rs_[2][4] = {}, rq_[2][4] = {};
    #pragma unroll
    for (int j = 0; j < 8; ++j) {
        const int c = wn + j * 16 + l15;
        const float bo_c = bo[c];
        #pragma unroll
        for (int i = 0; i < 2; ++i) {
            const int sb = s0 + i * 16 + quad * 4;
            const f32x4 res = *(const f32x4*)(img + ((size_t)b * CCH + c) * HW + sb);
            #pragma unroll
            for (int r = 0; r < 4; ++r) {
                const float y = acc[i][j][r] + bo_c + res[r];
                acc[i][j][r] = y;
                rs_[i][r] += y;
                rq_[i][r] += y * y;
            }
        }
    }
    // reduce across the 16 l15 lanes (c within chunk)
    #pragma unroll
    for (int i = 0; i < 2; ++i)
        #pragma unroll
        for (int r = 0; r < 4; ++r) {
            #pragma unroll
            for (int m = 1; m < 16; m <<= 1) {
                rs_[i][r] += __shfl_xor(rs_[i][r], m, 64);
                rq_[i][r] += __shfl_xor(rq_[i][r], m, 64);
            }
        }
    if (l15 == 0) {
        #pragma unroll
        for (int i = 0; i < 2; ++i)
            #pragma unroll
            for (int r = 0; r < 4; ++r) {
                redS[0][i * 16 + quad * 4 + r][wave] = rs_[i][r];
                redS[1][i * 16 + quad * 4 + r][wave] = rq_[i][r];
            }
    }
    __syncthreads();

    float mu[2][4], rstd[2][4];
    #pragma unroll
    for (int i = 0; i < 2; ++i)
        #pragma unroll
        for (int r = 0; r < 4; ++r) {
            const int s = i * 16 + quad * 4 + r;
            const float sm = redS[0][s][0] + redS[0][s][1] + redS[0][s][2] + redS[0][s][3];
            const float sq = redS[1][s][0] + redS[1][s][1] + redS[1][s][2] + redS[1][s][3];
            const float m_ = sm * (1.f / 512.f);
            mu[i][r] = m_;
            rstd[i][r] = rsqrtf(sq * (1.f / 512.f) - m_ * m_ + EPS);
        }

    // Pass 2: normalize + scale/shift + direct f32x4 store to [b][c][s]
    #pragma unroll
    for (int j = 0; j < 8; ++j) {
        const int c = wn + j * 16 + l15;
        const float g_c = gamma[c];
        const float be_c = beta[c];
        #pragma unroll
        for (int i = 0; i < 2; ++i) {
            const int sb = s0 + i * 16 + quad * 4;
            f32x4 z;
            #pragma unroll
            for (int r = 0; r < 4; ++r)
                z[r] = (acc[i][j][r] - mu[i][r]) * rstd[i][r] * g_c + be_c;
            *(f32x4*)(out + ((size_t)b * CCH + c) * HW + sb) = z;
        }
    }
}

// ---------------------------------------------------------------------------
extern "C" void kernel_launch(void* const* d_in, const int* in_sizes, int n_in,
                              void* d_out, int out_size, void* d_ws, size_t ws_size,
                              hipStream_t stream) {
    const float* img   = (const float*)d_in[0];
    const float* audio = (const float*)d_in[1];
    const float* Wq    = (const float*)d_in[2];
    const float* bq    = (const float*)d_in[3];
    const float* Wk    = (const float*)d_in[4];
    const float* bk    = (const float*)d_in[5];
    const float* Wv    = (const float*)d_in[6];
    const float* bv    = (const float*)d_in[7];
    const float* Wo    = (const float*)d_in[8];
    const float* bo    = (const float*)d_in[9];
    const float* gamma = (const float*)d_in[10];
    const float* beta  = (const float*)d_in[11];

    bf16* wsb    = (bf16*)d_ws;
    bf16* wT     = wsb;                     // 4*262144 (q,k,v,o)
    bf16* q_bf   = wT + 1048576;            // 8388608
    bf16* kh_bf  = q_bf + 8388608;          // 2097152  [B][H][256][64]
    bf16* vt_bf  = kh_bf + 2097152;         // 2097152  [B][H][64][256]
    bf16* a_bf   = vt_bf + 2097152;         // 8388608

    // 1) weight transposes/casts
    tc_w<<<dim3(8, 8, 4), 256, 0, stream>>>(Wq, Wk, Wv, Wo, wT);
    // 2) Q (raw img, in-staging transpose) + K|V projections
    gemm_qkv<<<dim3(768), 256, 0, stream>>>(img, audio, wT, bq, bk, bv,
                                            q_bf, kh_bf, vt_bf);
    // 3) attention
    attn_mfma<<<dim3(B_SZ * N_HEADS, HW / 64), 256, 0, stream>>>(q_bf, kh_bf, vt_bf, a_bf);
    // 4) out-projection + residual (raw f32 img) + LayerNorm + store
    gemm_oln<<<dim3(512), 256, 0, stream>>>(a_bf, wT + 3 * 262144, bo, img,
                                            gamma, beta, (float*)d_out);
}